// Round 1
// 412.611 us; speedup vs baseline: 1.0944x; 1.0944x over previous
//
#include <hip/hip_runtime.h>
#include <hip/hip_bf16.h>
#include <float.h>

#define BATCH 8
#define CDIM 64
#define NPTS 4096
#define KNN 20
#define KSEL 32
#define BUFCAP 96
#define BN_EPS 1e-5f
#define NEG_SLOPE 0.2f

typedef __attribute__((ext_vector_type(8))) short short8;
typedef __attribute__((ext_vector_type(4))) float float4v;
typedef unsigned short ushort;
typedef unsigned int uint;
typedef unsigned long long ull;

__device__ __forceinline__ ushort f2bf(float f) {
    uint u = __float_as_uint(f);
    u += 0x7FFF + ((u >> 16) & 1);            // round-to-nearest-even
    return (ushort)(u >> 16);
}
__device__ __forceinline__ int mbcnt64(ull m) {
    int c = __builtin_amdgcn_mbcnt_lo((uint)m, 0);
    return __builtin_amdgcn_mbcnt_hi((uint)(m >> 32), c);
}

// Find 33rd-smallest key in buf[0..cnt), compact keys < K33 to front,
// set cnt to kept count (==32 when cnt>=33). Returns K33 (new tau).
// Safe with BUFCAP=96: a post-truncate append adds <=64 to cnt=32.
__device__ __forceinline__ uint select33_truncate(uint* __restrict__ buf,
                                                  int& cnt, int lane) {
    uint e0 = 0xFFFFFFFFu, e1 = 0xFFFFFFFFu;
    if (lane < cnt) e0 = buf[lane];
    if (64 + lane < cnt) e1 = buf[64 + lane];
    uint p = 0;
    for (int bit = 31; bit >= 0; --bit) {
        uint t = p | (1u << bit);
        ull mA = __ballot(e0 < t);
        ull mB = __ballot(e1 < t);
        if (__popcll(mA) + __popcll(mB) < 33) p = t;   // uniform
    }
    ull mA = __ballot(e0 < p);
    ull mB = __ballot(e1 < p);
    int pA = __popcll(mA);
    int r0 = mbcnt64(mA);
    int r1 = pA + mbcnt64(mB);
    if (e0 < p) buf[r0] = e0;
    if (e1 < p) buf[r1] = e1;
    cnt = pA + __popcll(mB);
    return p;
}

// Streaming append of one candidate column (key = 20-bit dist | 12-bit idx).
// All control conditions are wave-uniform (ballot results / per-row scalars).
__device__ __forceinline__ void scan_append(float dwv, float base, int idx,
                                            uint& tau, int& cnt,
                                            uint* __restrict__ buf, int lane) {
    float dval = fmaxf(fmaf(-2.f, dwv, base), 0.f);
    uint key = (__float_as_uint(dval) & 0xFFFFF000u) | (uint)idx;
    ull mask = __ballot(key < tau);
    if (mask) {
        int c = __popcll(mask);
        if (cnt + c > BUFCAP) {
            tau = select33_truncate(buf, cnt, lane);
            mask = __ballot(key < tau);
            c = __popcll(mask);
        }
        if (c) {
            int rank = mbcnt64(mask);
            if (key < tau) buf[cnt + rank] = key;
            cnt += c;
        }
    }
}

// ---------------------------------------------------------------------------
// K1: x [B,C,N] -> xt [B,N,64] fp32, xh bf16, sq[b,n].
// (single-bf16 kNN: no lo-part needed; exact fp32 refine re-ranks top-32)
// ---------------------------------------------------------------------------
__global__ void k_prep(const float* __restrict__ x,
                       float* __restrict__ xt,
                       ushort* __restrict__ xh,
                       float* __restrict__ sq) {
    int gid = blockIdx.x * 256 + threadIdx.x;     // [0, B*N)
    int b = gid >> 12;
    int n = gid & (NPTS - 1);
    const float* xb = x + (size_t)b * CDIM * NPTS + n;
    float acc = 0.f;
    float4* xtv = (float4*)(xt + ((size_t)gid << 6));
    uint2* xhp = (uint2*)(xh + ((size_t)gid << 6));
    #pragma unroll
    for (int q = 0; q < 16; ++q) {
        float v[4]; ushort h[4];
        #pragma unroll
        for (int j = 0; j < 4; ++j) {
            float tv = xb[(q * 4 + j) * NPTS];    // coalesced across n
            v[j] = tv;
            acc = fmaf(tv, tv, acc);
            h[j] = f2bf(tv);
        }
        xtv[q] = make_float4(v[0], v[1], v[2], v[3]);
        uint2 ph;
        ph.x = (uint)h[0] | ((uint)h[1] << 16);
        ph.y = (uint)h[2] | ((uint)h[3] << 16);
        xhp[q] = ph;
    }
    sq[gid] = acc;
}

// ---------------------------------------------------------------------------
// K2: p = W1 @ x, z = (W2-W1) @ x, stored transposed: pt/zt [B,N,64]
// ---------------------------------------------------------------------------
__global__ void k_pz(const float* __restrict__ xt, const float* __restrict__ W,
                     float* __restrict__ pt, float* __restrict__ zt) {
    int b  = blockIdx.x >> 6;
    int n0 = (blockIdx.x & 63) << 6;
    int lane = threadIdx.x & 63;
    int w = threadIdx.x >> 6;
    int n = n0 + lane;
    size_t rowoff = ((size_t)(b * NPTS + n)) << 6;
    const float4* xrow = (const float4*)(xt + rowoff);
    float acc1[16], acc2[16];
    #pragma unroll
    for (int i = 0; i < 16; ++i) { acc1[i] = 0.f; acc2[i] = 0.f; }
    #pragma unroll
    for (int cg = 0; cg < 4; ++cg) {
        float xv[16];
        #pragma unroll
        for (int q = 0; q < 4; ++q) {
            float4 t = xrow[cg * 4 + q];
            xv[q*4] = t.x; xv[q*4+1] = t.y; xv[q*4+2] = t.z; xv[q*4+3] = t.w;
        }
        #pragma unroll
        for (int oi = 0; oi < 16; ++oi) {
            int o = (w << 4) + oi;
            const float* wr = W + o * 128 + cg * 16;
            float a1 = acc1[oi], a2 = acc2[oi];
            #pragma unroll
            for (int j = 0; j < 16; ++j) {
                a1 = fmaf(wr[j],      xv[j], a1);
                a2 = fmaf(wr[64 + j], xv[j], a2);
            }
            acc1[oi] = a1; acc2[oi] = a2;
        }
    }
    float4* pv = (float4*)(pt + rowoff + (w << 4));
    float4* zv = (float4*)(zt + rowoff + (w << 4));
    #pragma unroll
    for (int q = 0; q < 4; ++q) {
        pv[q] = make_float4(acc1[q*4], acc1[q*4+1], acc1[q*4+2], acc1[q*4+3]);
        zv[q] = make_float4(acc2[q*4]   - acc1[q*4],
                            acc2[q*4+1] - acc1[q*4+1],
                            acc2[q*4+2] - acc1[q*4+2],
                            acc2[q*4+3] - acc1[q*4+3]);
    }
}

// ---------------------------------------------------------------------------
// K3: single-bf16 MFMA kNN, ONE barrier per 64-candidate chunk.
// Double-buffered B tiles (Bh[2]) and distance tiles (dw[2]); scan of chunk
// c-1 overlaps staging of c+1 and MFMA of c inside one barrier interval.
// Selection machinery (packed-key mbcnt-append + ballot-bisection select-33)
// unchanged from the proven R8 structure; only dist precision is bf16 single
// (exact fp32 sq terms), which the exact fp32 refine over top-32 tolerates
// (rank-20..33 gap ~2.8 >> bf16 dot error sigma ~0.05).
// Hazard ledger (all pairs separated by exactly one barrier):
//   stage Bh[p^1] @c   vs frag-read Bh[p^1] @c-1
//   frag-read Bh[p] @c vs stage Bh[p]       @c-1
//   dw[p] write @c     vs dw[p] scan        @c+1
//   dw[p^1] scan @c    vs dw[p^1] write     @c+1
// ---------------------------------------------------------------------------
__global__ void __launch_bounds__(512) k_knn(
        const ushort* __restrict__ xh,
        const float* __restrict__ sq, ushort* __restrict__ knn32) {
    __shared__ ushort Bh[2][64][72];          // +8 pad (144B rows, 16B aligned)
    __shared__ float dw[2][2][16][68];        // per-parity per-group dist tile
    __shared__ uint rowbuf[32 * BUFCAP];      // 8 waves x 4 rows x 96

    int tid  = threadIdx.x;
    int wv   = tid >> 6;              // wave 0..7
    int lane = tid & 63;
    int g    = wv >> 2;               // row-group 0..1
    int t    = wv & 3;                // wave-in-group
    int b    = blockIdx.x >> 7;       // 128 blocks per batch
    int r0   = ((blockIdx.x & 127) << 5) + (g << 4);   // group base row
    int col  = lane & 15;
    int quad = lane >> 4;

    // A fragments (chunk-invariant): row = r0 + col, k = quad*8 + j
    size_t arow = ((size_t)(b * NPTS + r0 + col)) << 6;
    short8 ah0 = *(const short8*)(xh + arow + quad * 8);
    short8 ah1 = *(const short8*)(xh + arow + 32 + quad * 8);

    const ushort* xhb = xh + (((size_t)b * NPTS) << 6);
    const float* sqb = sq + b * NPTS;
    int spt = tid >> 3, seg = tid & 7;    // 64 pts x 8 segs of 8 ushorts

    uint tau[4];
    int cnt[4];
    float sqr[4];
    uint* buf[4];
    #pragma unroll
    for (int r = 0; r < 4; ++r) {
        tau[r] = 0xFFFFFFFFu; cnt[r] = 0;
        sqr[r] = sqb[r0 + (t << 2) + r];
        buf[r] = rowbuf + ((wv << 2) + r) * BUFCAP;
    }

    // stage chunk 0; prefetch chunk 1; pipeline candidate-sq one chunk ahead
    {
        uint4 v0 = *(const uint4*)(xhb + (((size_t)spt) << 6) + seg * 8);
        *(uint4*)&Bh[0][spt][seg * 8] = v0;
    }
    uint4 vpre = *(const uint4*)(xhb + (((size_t)(64 + spt)) << 6) + seg * 8);
    float sv_cur = 0.f;               // sq of chunk (c-1) candidates at lane
    float sv_nxt = sqb[lane];         // sq of chunk c candidates at lane
    __syncthreads();

    for (int c = 0; c < 64; ++c) {
        int q = c & 1;

        // stage chunk c+1 into the other parity; issue prefetch for c+2
        if (c < 63)
            *(uint4*)&Bh[q ^ 1][spt][seg * 8] = vpre;
        if (c < 62)
            vpre = *(const uint4*)(xhb +
                       (((size_t)(((c + 2) << 6) + spt)) << 6) + seg * 8);

        // this wave's tile for chunk c: cands [16t,16t+16), rows [r0,r0+16)
        {
            int bp = (t << 4) + col;
            short8 bh0 = *(const short8*)&Bh[q][bp][quad * 8];
            short8 bh1 = *(const short8*)&Bh[q][bp][32 + quad * 8];
            float4v acc = {0.f, 0.f, 0.f, 0.f};
            acc = __builtin_amdgcn_mfma_f32_16x16x32_bf16(ah0, bh0, acc, 0, 0, 0);
            acc = __builtin_amdgcn_mfma_f32_16x16x32_bf16(ah1, bh1, acc, 0, 0, 0);
            #pragma unroll
            for (int r = 0; r < 4; ++r)
                dw[q][g][(quad << 2) + r][(t << 4) + col] = acc[r];
        }

        // scan chunk c-1 (dw parity q^1); lane = candidate
        if (c > 0) {
            int m0 = (c - 1) << 6;
            float d0 = dw[q ^ 1][g][(t << 2) + 0][lane];
            float d1 = dw[q ^ 1][g][(t << 2) + 1][lane];
            float d2 = dw[q ^ 1][g][(t << 2) + 2][lane];
            float d3 = dw[q ^ 1][g][(t << 2) + 3][lane];
            scan_append(d0, sv_cur + sqr[0], m0 + lane, tau[0], cnt[0], buf[0], lane);
            scan_append(d1, sv_cur + sqr[1], m0 + lane, tau[1], cnt[1], buf[1], lane);
            scan_append(d2, sv_cur + sqr[2], m0 + lane, tau[2], cnt[2], buf[2], lane);
            scan_append(d3, sv_cur + sqr[3], m0 + lane, tau[3], cnt[3], buf[3], lane);
        }

        // rotate candidate-sq pipeline (every interval, incl. c==0)
        sv_cur = sv_nxt;
        if (c < 63) sv_nxt = sqb[((c + 1) << 6) + lane];

        __syncthreads();   // single barrier per chunk
    }

    // drain: scan chunk 63 (dw parity 1); loop's final barrier ordered it
    {
        int m0 = 63 << 6;
        float d0 = dw[1][g][(t << 2) + 0][lane];
        float d1 = dw[1][g][(t << 2) + 1][lane];
        float d2 = dw[1][g][(t << 2) + 2][lane];
        float d3 = dw[1][g][(t << 2) + 3][lane];
        scan_append(d0, sv_cur + sqr[0], m0 + lane, tau[0], cnt[0], buf[0], lane);
        scan_append(d1, sv_cur + sqr[1], m0 + lane, tau[1], cnt[1], buf[1], lane);
        scan_append(d2, sv_cur + sqr[2], m0 + lane, tau[2], cnt[2], buf[2], lane);
        scan_append(d3, sv_cur + sqr[3], m0 + lane, tau[3], cnt[3], buf[3], lane);
    }

    // final extraction: exact key-top-32 per row
    #pragma unroll
    for (int r = 0; r < 4; ++r) {
        select33_truncate(buf[r], cnt[r], lane);
        if (lane < KSEL) {
            uint e = buf[r][lane];
            knn32[(size_t)(b * NPTS + r0 + (t << 2) + r) * KSEL + lane] =
                (ushort)(e & 0xFFFu);
        }
    }
}

// ---------------------------------------------------------------------------
// K3b: exact fp32 refinement — TWO rows per wave (half-wave per row, no idle
// lanes): 32 candidates in each half's lanes, exact fp32 distances, rank
// lexicographically (dist, idx) per np tie rule, emit top-20 set.
// ---------------------------------------------------------------------------
__global__ void __launch_bounds__(256) k_refine(
        const float* __restrict__ xt, const float* __restrict__ sq,
        const ushort* __restrict__ knn32, int* __restrict__ idx20) {
    int wvid = (blockIdx.x << 2) + (threadIdx.x >> 6);  // wave id [0, B*N/2)
    int lane = threadIdx.x & 63;
    int half = lane >> 5;
    int sl   = lane & 31;
    int row  = (wvid << 1) + half;                      // row id [0, B*N)
    int b = row >> 12;
    int cand = knn32[(size_t)row * KSEL + sl];
    const float4* xc = (const float4*)(xt + ((size_t)(b * NPTS + cand) << 6));
    const float4* xr = (const float4*)(xt + ((size_t)row << 6));
    float acc = 0.f;
    #pragma unroll
    for (int q = 0; q < 16; ++q) {
        float4 a = xr[q], c = xc[q];
        acc = fmaf(a.x, c.x, acc); acc = fmaf(a.y, c.y, acc);
        acc = fmaf(a.z, c.z, acc); acc = fmaf(a.w, c.w, acc);
    }
    float d = fmaf(-2.f, acc, sq[b * NPTS + cand]);
    int rank = 0;
    int base = half << 5;
    #pragma unroll
    for (int j = 0; j < KSEL; ++j) {
        float dj = __shfl(d, base + j);
        int   cj = __shfl(cand, base + j);
        rank += ((dj < d) || (dj == d && cj < cand)) ? 1 : 0;
    }
    if (rank < KNN)
        idx20[(size_t)row * KNN + rank] = cand;
}

// ---------------------------------------------------------------------------
// K4: gather p columns per neighbor; per-(b,n) max/min/sum/sumsq over k;
// write tmax/tmin = (max/min_k p[idx]) + z; accumulate channel sums.
// ---------------------------------------------------------------------------
__global__ void k_gather(const float* __restrict__ pt, const float* __restrict__ zt,
                         const int* __restrict__ idxin,
                         float* __restrict__ tmax, float* __restrict__ tmin,
                         float* __restrict__ S1, float* __restrict__ S2) {
    __shared__ float red1[4][64];
    __shared__ float red2[4][64];
    int b  = blockIdx.x >> 6;
    int n0 = (blockIdx.x & 63) << 6;
    int lane = threadIdx.x & 63;
    int w = threadIdx.x >> 6;
    float cs1 = 0.f, cs2 = 0.f;
    for (int i = 0; i < 16; ++i) {
        int n = n0 + (w << 4) + i;
        int base = b * NPTS + n;
        int ibase = __builtin_amdgcn_readfirstlane(base * KNN);
        const int* ip = idxin + ibase;
        float mx = -FLT_MAX, mn = FLT_MAX, s1 = 0.f, s2 = 0.f;
        #pragma unroll
        for (int k = 0; k < KNN; ++k) {
            int colp = ip[k];                              // SGPR
            float v = pt[(((size_t)(b * NPTS + colp)) << 6) + lane]; // coalesced
            mx = fmaxf(mx, v); mn = fminf(mn, v);
            s1 += v; s2 = fmaf(v, v, s2);
        }
        float z = zt[(((size_t)base) << 6) + lane];
        tmax[(((size_t)base) << 6) + lane] = mx + z;
        tmin[(((size_t)base) << 6) + lane] = mn + z;
        cs1 += s1 + (float)KNN * z;
        cs2 += s2 + 2.f * z * s1 + (float)KNN * z * z;
    }
    red1[w][lane] = cs1;
    red2[w][lane] = cs2;
    __syncthreads();
    if (threadIdx.x < 64) {
        float t1 = red1[0][lane] + red1[1][lane] + red1[2][lane] + red1[3][lane];
        float t2 = red2[0][lane] + red2[1][lane] + red2[2][lane] + red2[3][lane];
        atomicAdd(&S1[lane], t1);
        atomicAdd(&S2[lane], t2);
    }
}

// ---------------------------------------------------------------------------
// K5: finalize BN stats, affine + LeakyReLU, transpose to out [B,64,N].
// ---------------------------------------------------------------------------
__global__ void k_final(const float* __restrict__ tmax, const float* __restrict__ tmin,
                        const float* __restrict__ S1, const float* __restrict__ S2,
                        const float* __restrict__ gamma, const float* __restrict__ beta,
                        float* __restrict__ out) {
    __shared__ float smx[64][65];
    __shared__ float smn[64][65];
    int b  = blockIdx.x >> 6;
    int n0 = (blockIdx.x & 63) << 6;
    int lane = threadIdx.x & 63;
    int w = threadIdx.x >> 6;
    #pragma unroll
    for (int i = 0; i < 16; ++i) {
        int nl = (i << 2) + w;
        size_t off = (((size_t)(b * NPTS + n0 + nl)) << 6) + lane;
        smx[nl][lane] = tmax[off];
        smn[nl][lane] = tmin[off];
    }
    __syncthreads();
    const float inv_cnt = 1.0f / ((float)BATCH * NPTS * KNN);
    #pragma unroll
    for (int i = 0; i < 16; ++i) {
        int o = (i << 2) + w;
        float s1 = S1[o], s2 = S2[o];
        float mean = s1 * inv_cnt;
        float var = fmaf(-mean, mean, s2 * inv_cnt);
        float rs = rsqrtf(var + BN_EPS);
        float sc = gamma[o] * rs;
        float sh = beta[o] - mean * sc;
        float tv = (sc >= 0.f) ? smx[lane][o] : smn[lane][o];
        float y = fmaf(tv, sc, sh);
        y = (y >= 0.f) ? y : NEG_SLOPE * y;
        out[((size_t)(b * 64 + o)) * NPTS + n0 + lane] = y;
    }
}

// ---------------------------------------------------------------------------
extern "C" void kernel_launch(void* const* d_in, const int* in_sizes, int n_in,
                              void* d_out, int out_size, void* d_ws, size_t ws_size,
                              hipStream_t stream) {
    const float* x     = (const float*)d_in[0];   // [8,64,4096]
    const float* W     = (const float*)d_in[1];   // [64,128]
    const float* gamma = (const float*)d_in[2];   // [64]
    const float* beta  = (const float*)d_in[3];   // [64]
    float* out = (float*)d_out;                   // [8,64,4096]

    float* ws = (float*)d_ws;
    const size_t SECT = (size_t)BATCH * NPTS * 64;      // 2,097,152
    float*  xt    = ws;
    float*  pt    = ws + SECT;
    float*  zt    = ws + 2 * SECT;
    float*  sq    = ws + 3 * SECT;                       // 32768
    float*  S1    = ws + 3 * SECT + 32768;               // 64
    float*  S2    = S1 + 64;
    int*    idx20 = (int*)(ws + 3 * SECT + 32768 + 128); // 655,360 ints
    float*  uA    = ws + 3 * SECT + 32768 + 128 + 655360;
    // union A:
    //   phase 1 (prep..refine): xh (SECT ushorts) | knn32 (B*N*32 ushorts)
    //   phase 2 (gather..final): tmx | tmn
    ushort* xh    = (ushort*)uA;                         // SECT ushorts
    ushort* knn32 = (ushort*)(uA + SECT / 2);            // B*N*32 ushorts
    float*  tmx   = uA;                                  // SECT floats
    float*  tmn   = uA + SECT;                           // SECT floats

    hipMemsetAsync(S1, 0, 2 * 64 * sizeof(float), stream);
    k_prep  <<<dim3((BATCH * NPTS) / 256), dim3(256), 0, stream>>>(x, xt, xh, sq);
    k_pz    <<<dim3(BATCH * (NPTS / 64)), dim3(256), 0, stream>>>(xt, W, pt, zt);
    k_knn   <<<dim3(1024), dim3(512), 0, stream>>>(xh, sq, knn32);
    k_refine<<<dim3((BATCH * NPTS) / 8), dim3(256), 0, stream>>>(xt, sq, knn32, idx20);
    k_gather<<<dim3(BATCH * (NPTS / 64)), dim3(256), 0, stream>>>(pt, zt, idx20, tmx, tmn, S1, S2);
    k_final <<<dim3(BATCH * (NPTS / 64)), dim3(256), 0, stream>>>(tmx, tmn, S1, S2, gamma, beta, out);
}

// Round 3
// 362.516 us; speedup vs baseline: 1.2456x; 1.1382x over previous
//
#include <hip/hip_runtime.h>
#include <hip/hip_bf16.h>
#include <float.h>

#define BATCH 8
#define CDIM 64
#define NPTS 4096
#define KNN 20
#define KSEL 32
#define BUFCAP 128
#define BN_EPS 1e-5f
#define NEG_SLOPE 0.2f

typedef __attribute__((ext_vector_type(8))) short short8;
typedef __attribute__((ext_vector_type(4))) float float4v;
typedef unsigned short ushort;
typedef unsigned int uint;
typedef unsigned long long ull;

__device__ __forceinline__ ushort f2bf(float f) {
    uint u = __float_as_uint(f);
    u += 0x7FFF + ((u >> 16) & 1);            // round-to-nearest-even
    return (ushort)(u >> 16);
}
__device__ __forceinline__ int mbcnt64(ull m) {
    int c = __builtin_amdgcn_mbcnt_lo((uint)m, 0);
    return __builtin_amdgcn_mbcnt_hi((uint)(m >> 32), c);
}

// Find 33rd-smallest key in buf[0..cnt), compact keys < K33 to front,
// set cnt to kept count (==32 when cnt>=33; keys distinct). Returns K33.
// Requires cnt <= 128 (two elements per lane).
__device__ __forceinline__ uint select33_truncate(uint* __restrict__ buf,
                                                  int& cnt, int lane) {
    uint e0 = 0xFFFFFFFFu, e1 = 0xFFFFFFFFu;
    if (lane < cnt) e0 = buf[lane];
    if (64 + lane < cnt) e1 = buf[64 + lane];
    uint p = 0;
    for (int bit = 31; bit >= 0; --bit) {
        uint t = p | (1u << bit);
        ull mA = __ballot(e0 < t);
        ull mB = __ballot(e1 < t);
        if (__popcll(mA) + __popcll(mB) < 33) p = t;   // uniform
    }
    ull mA = __ballot(e0 < p);
    ull mB = __ballot(e1 < p);
    int pA = __popcll(mA);
    int r0 = mbcnt64(mA);
    int r1 = pA + mbcnt64(mB);
    if (e0 < p) buf[r0] = e0;
    if (e1 < p) buf[r1] = e1;
    cnt = pA + __popcll(mB);
    return p;
}

// Streaming append of one candidate column (key = 20-bit dist | 12-bit idx).
// All control conditions are wave-uniform (ballot results / per-row scalars).
__device__ __forceinline__ void scan_append(float dwv, float base, int idx,
                                            uint& tau, int& cnt,
                                            uint* __restrict__ buf, int lane) {
    float dval = fmaxf(fmaf(-2.f, dwv, base), 0.f);
    uint key = (__float_as_uint(dval) & 0xFFFFF000u) | (uint)idx;
    ull mask = __ballot(key < tau);
    if (mask) {
        int c = __popcll(mask);
        if (cnt + c > BUFCAP) {
            tau = select33_truncate(buf, cnt, lane);
            mask = __ballot(key < tau);
            c = __popcll(mask);
        }
        if (c) {
            int rank = mbcnt64(mask);
            if (key < tau) buf[cnt + rank] = key;
            cnt += c;
        }
    }
}

// ---------------------------------------------------------------------------
// K1: x [B,C,N] -> xt [B,N,64] fp32, xh bf16, sq[b,n].
// ---------------------------------------------------------------------------
__global__ void k_prep(const float* __restrict__ x,
                       float* __restrict__ xt,
                       ushort* __restrict__ xh,
                       float* __restrict__ sq) {
    int gid = blockIdx.x * 256 + threadIdx.x;     // [0, B*N)
    int b = gid >> 12;
    int n = gid & (NPTS - 1);
    const float* xb = x + (size_t)b * CDIM * NPTS + n;
    float acc = 0.f;
    float4* xtv = (float4*)(xt + ((size_t)gid << 6));
    uint2* xhp = (uint2*)(xh + ((size_t)gid << 6));
    #pragma unroll
    for (int q = 0; q < 16; ++q) {
        float v[4]; ushort h[4];
        #pragma unroll
        for (int j = 0; j < 4; ++j) {
            float tv = xb[(q * 4 + j) * NPTS];    // coalesced across n
            v[j] = tv;
            acc = fmaf(tv, tv, acc);
            h[j] = f2bf(tv);
        }
        xtv[q] = make_float4(v[0], v[1], v[2], v[3]);
        uint2 ph;
        ph.x = (uint)h[0] | ((uint)h[1] << 16);
        ph.y = (uint)h[2] | ((uint)h[3] << 16);
        xhp[q] = ph;
    }
    sq[gid] = acc;
}

// ---------------------------------------------------------------------------
// K2: p = W1 @ x, z = (W2-W1) @ x, stored transposed: pt/zt [B,N,64]
// ---------------------------------------------------------------------------
__global__ void k_pz(const float* __restrict__ xt, const float* __restrict__ W,
                     float* __restrict__ pt, float* __restrict__ zt) {
    int b  = blockIdx.x >> 6;
    int n0 = (blockIdx.x & 63) << 6;
    int lane = threadIdx.x & 63;
    int w = threadIdx.x >> 6;
    int n = n0 + lane;
    size_t rowoff = ((size_t)(b * NPTS + n)) << 6;
    const float4* xrow = (const float4*)(xt + rowoff);
    float acc1[16], acc2[16];
    #pragma unroll
    for (int i = 0; i < 16; ++i) { acc1[i] = 0.f; acc2[i] = 0.f; }
    #pragma unroll
    for (int cg = 0; cg < 4; ++cg) {
        float xv[16];
        #pragma unroll
        for (int q = 0; q < 4; ++q) {
            float4 t = xrow[cg * 4 + q];
            xv[q*4] = t.x; xv[q*4+1] = t.y; xv[q*4+2] = t.z; xv[q*4+3] = t.w;
        }
        #pragma unroll
        for (int oi = 0; oi < 16; ++oi) {
            int o = (w << 4) + oi;
            const float* wr = W + o * 128 + cg * 16;
            float a1 = acc1[oi], a2 = acc2[oi];
            #pragma unroll
            for (int j = 0; j < 16; ++j) {
                a1 = fmaf(wr[j],      xv[j], a1);
                a2 = fmaf(wr[64 + j], xv[j], a2);
            }
            acc1[oi] = a1; acc2[oi] = a2;
        }
    }
    float4* pv = (float4*)(pt + rowoff + (w << 4));
    float4* zv = (float4*)(zt + rowoff + (w << 4));
    #pragma unroll
    for (int q = 0; q < 4; ++q) {
        pv[q] = make_float4(acc1[q*4], acc1[q*4+1], acc1[q*4+2], acc1[q*4+3]);
        zv[q] = make_float4(acc2[q*4]   - acc1[q*4],
                            acc2[q*4+1] - acc1[q*4+1],
                            acc2[q*4+2] - acc1[q*4+2],
                            acc2[q*4+3] - acc1[q*4+3]);
    }
}

// ---------------------------------------------------------------------------
// K3: single-bf16 MFMA kNN, no LDS staging: B-fragments are read directly
// from global (per-batch xh slice = 512 KB, L2-resident), register
// ping-ponged one chunk ahead (explicit even/odd unroll — no runtime reg
// indexing). LDS holds only the dw distance tiles (parity double-buffer)
// and per-wave selection buffers -> 33.8 KB, 4 blocks/CU.
// Barrier is raw s_barrier + lgkmcnt(0) ONLY: all cross-wave hazards are
// LDS (dw parity ledger identical to R0); global frag/sq loads are
// wave-private and stay in flight across the barrier (counted-vmcnt idiom).
// Hazard ledger (each pair separated by exactly one barrier):
//   dw[q] write @c     vs dw[q] scan  @c+1
//   dw[q^1] scan @c    vs dw[q^1] write @c+1
// ---------------------------------------------------------------------------
__global__ void __launch_bounds__(512, 8) k_knn(
        const ushort* __restrict__ xh,
        const float* __restrict__ sq, ushort* __restrict__ knn32) {
    __shared__ float dw[2][2][16][68];        // per-parity per-group dist tile
    __shared__ uint rowbuf[32 * BUFCAP];      // 8 waves x 4 rows x 128

    int tid  = threadIdx.x;
    int wv   = tid >> 6;              // wave 0..7
    int lane = tid & 63;
    int g    = wv >> 2;               // row-group 0..1
    int t    = wv & 3;                // wave-in-group
    int b    = blockIdx.x >> 7;       // 128 blocks per batch
    int r0   = ((blockIdx.x & 127) << 5) + (g << 4);   // group base row
    int col  = lane & 15;
    int quad = lane >> 4;

    // A fragments (chunk-invariant): row = r0 + col, k = quad*8 + j
    size_t arow = ((size_t)(b * NPTS + r0 + col)) << 6;
    short8 ah0 = *(const short8*)(xh + arow + quad * 8);
    short8 ah1 = *(const short8*)(xh + arow + 32 + quad * 8);

    const ushort* xhb = xh + (((size_t)b * NPTS) << 6);
    const float* sqb = sq + b * NPTS;
    // B-frag base for this lane: point (t*16+col) of chunk 0
    const ushort* fbase = xhb + (((size_t)((t << 4) + col)) << 6) + (quad << 3);

    uint tau[4];
    int cnt[4];
    float sqr[4];
    uint* wbuf = rowbuf + ((wv << 2) * BUFCAP);
    #pragma unroll
    for (int r = 0; r < 4; ++r) {
        tau[r] = 0xFFFFFFFFu; cnt[r] = 0;
        sqr[r] = sqb[r0 + (t << 2) + r];
    }

    // prologue: frags + candidate-sq for chunk 0
    short8 fA0 = *(const short8*)fbase;
    short8 fA1 = *(const short8*)(fbase + 32);
    short8 fB0, fB1;
    float sv_cur = 0.f;               // sq of chunk (c-1) candidates at lane
    float sv_nxt = sqb[lane];         // sq of chunk c candidates at lane

    auto step = [&](int c, int q, short8& f0, short8& f1,
                    short8& nf0, short8& nf1) {
        // issue next-chunk frag + sq loads early (stay in flight over barrier)
        if (c + 1 < 64) {
            const ushort* p = fbase + (((size_t)(c + 1)) << 12);
            nf0 = *(const short8*)p;
            nf1 = *(const short8*)(p + 32);
        }
        float sv_tmp = (c + 1 < 64) ? sqb[((c + 1) << 6) + lane] : 0.f;

        // MFMA for chunk c: cands [16t,16t+16), rows [r0,r0+16)
        float4v acc = {0.f, 0.f, 0.f, 0.f};
        acc = __builtin_amdgcn_mfma_f32_16x16x32_bf16(ah0, f0, acc, 0, 0, 0);
        acc = __builtin_amdgcn_mfma_f32_16x16x32_bf16(ah1, f1, acc, 0, 0, 0);
        #pragma unroll
        for (int r = 0; r < 4; ++r)
            dw[q][g][(quad << 2) + r][(t << 4) + col] = acc[r];

        // scan chunk c-1 (dw parity q^1); lane = candidate
        if (c > 0) {
            int m0 = (c - 1) << 6;
            #pragma unroll
            for (int r = 0; r < 4; ++r) {
                float dv = dw[q ^ 1][g][(t << 2) + r][lane];
                scan_append(dv, sv_cur + sqr[r], m0 + lane, tau[r], cnt[r],
                            wbuf + r * BUFCAP, lane);
            }
        }
        sv_cur = sv_nxt;
        sv_nxt = sv_tmp;

        // raw barrier: order LDS (dw, rowbuf) only; vmem stays in flight
        __builtin_amdgcn_sched_barrier(0);
        asm volatile("s_waitcnt lgkmcnt(0)" ::: "memory");
        __builtin_amdgcn_s_barrier();
        __builtin_amdgcn_sched_barrier(0);
    };

    for (int c = 0; c < 64; c += 2) {
        step(c,     0, fA0, fA1, fB0, fB1);
        step(c + 1, 1, fB0, fB1, fA0, fA1);
    }

    // drain: scan chunk 63 (dw parity 1); loop's final barrier ordered it
    {
        int m0 = 63 << 6;
        #pragma unroll
        for (int r = 0; r < 4; ++r) {
            float dv = dw[1][g][(t << 2) + r][lane];
            scan_append(dv, sv_cur + sqr[r], m0 + lane, tau[r], cnt[r],
                        wbuf + r * BUFCAP, lane);
        }
    }

    // final extraction: exact key-top-32 per row
    #pragma unroll
    for (int r = 0; r < 4; ++r) {
        select33_truncate(wbuf + r * BUFCAP, cnt[r], lane);
        if (lane < KSEL) {
            uint e = wbuf[r * BUFCAP + lane];
            knn32[(size_t)(b * NPTS + r0 + (t << 2) + r) * KSEL + lane] =
                (ushort)(e & 0xFFFu);
        }
    }
}

// ---------------------------------------------------------------------------
// K3b: exact fp32 refinement — TWO rows per wave (half-wave per row, no idle
// lanes): 32 candidates in each half's lanes, exact fp32 distances, rank
// lexicographically (dist, idx) per np tie rule, emit top-20 set.
// ---------------------------------------------------------------------------
__global__ void __launch_bounds__(256) k_refine(
        const float* __restrict__ xt, const float* __restrict__ sq,
        const ushort* __restrict__ knn32, int* __restrict__ idx20) {
    int wvid = (blockIdx.x << 2) + (threadIdx.x >> 6);  // wave id [0, B*N/2)
    int lane = threadIdx.x & 63;
    int half = lane >> 5;
    int sl   = lane & 31;
    int row  = (wvid << 1) + half;                      // row id [0, B*N)
    int b = row >> 12;
    int cand = knn32[(size_t)row * KSEL + sl];
    const float4* xc = (const float4*)(xt + ((size_t)(b * NPTS + cand) << 6));
    const float4* xr = (const float4*)(xt + ((size_t)row << 6));
    float acc = 0.f;
    #pragma unroll
    for (int q = 0; q < 16; ++q) {
        float4 a = xr[q], c = xc[q];
        acc = fmaf(a.x, c.x, acc); acc = fmaf(a.y, c.y, acc);
        acc = fmaf(a.z, c.z, acc); acc = fmaf(a.w, c.w, acc);
    }
    float d = fmaf(-2.f, acc, sq[b * NPTS + cand]);
    int rank = 0;
    int base = half << 5;
    #pragma unroll
    for (int j = 0; j < KSEL; ++j) {
        float dj = __shfl(d, base + j);
        int   cj = __shfl(cand, base + j);
        rank += ((dj < d) || (dj == d && cj < cand)) ? 1 : 0;
    }
    if (rank < KNN)
        idx20[(size_t)row * KNN + rank] = cand;
}

// ---------------------------------------------------------------------------
// K4: gather p columns per neighbor; per-(b,n) max/min/sum/sumsq over k;
// write tmax/tmin = (max/min_k p[idx]) + z; accumulate channel sums.
// ---------------------------------------------------------------------------
__global__ void k_gather(const float* __restrict__ pt, const float* __restrict__ zt,
                         const int* __restrict__ idxin,
                         float* __restrict__ tmax, float* __restrict__ tmin,
                         float* __restrict__ S1, float* __restrict__ S2) {
    __shared__ float red1[4][64];
    __shared__ float red2[4][64];
    int b  = blockIdx.x >> 6;
    int n0 = (blockIdx.x & 63) << 6;
    int lane = threadIdx.x & 63;
    int w = threadIdx.x >> 6;
    float cs1 = 0.f, cs2 = 0.f;
    for (int i = 0; i < 16; ++i) {
        int n = n0 + (w << 4) + i;
        int base = b * NPTS + n;
        int ibase = __builtin_amdgcn_readfirstlane(base * KNN);
        const int* ip = idxin + ibase;
        float mx = -FLT_MAX, mn = FLT_MAX, s1 = 0.f, s2 = 0.f;
        #pragma unroll
        for (int k = 0; k < KNN; ++k) {
            int colp = ip[k];                              // SGPR
            float v = pt[(((size_t)(b * NPTS + colp)) << 6) + lane]; // coalesced
            mx = fmaxf(mx, v); mn = fminf(mn, v);
            s1 += v; s2 = fmaf(v, v, s2);
        }
        float z = zt[(((size_t)base) << 6) + lane];
        tmax[(((size_t)base) << 6) + lane] = mx + z;
        tmin[(((size_t)base) << 6) + lane] = mn + z;
        cs1 += s1 + (float)KNN * z;
        cs2 += s2 + 2.f * z * s1 + (float)KNN * z * z;
    }
    red1[w][lane] = cs1;
    red2[w][lane] = cs2;
    __syncthreads();
    if (threadIdx.x < 64) {
        float t1 = red1[0][lane] + red1[1][lane] + red1[2][lane] + red1[3][lane];
        float t2 = red2[0][lane] + red2[1][lane] + red2[2][lane] + red2[3][lane];
        atomicAdd(&S1[lane], t1);
        atomicAdd(&S2[lane], t2);
    }
}

// ---------------------------------------------------------------------------
// K5: finalize BN stats, affine + LeakyReLU, transpose to out [B,64,N].
// ---------------------------------------------------------------------------
__global__ void k_final(const float* __restrict__ tmax, const float* __restrict__ tmin,
                        const float* __restrict__ S1, const float* __restrict__ S2,
                        const float* __restrict__ gamma, const float* __restrict__ beta,
                        float* __restrict__ out) {
    __shared__ float smx[64][65];
    __shared__ float smn[64][65];
    int b  = blockIdx.x >> 6;
    int n0 = (blockIdx.x & 63) << 6;
    int lane = threadIdx.x & 63;
    int w = threadIdx.x >> 6;
    #pragma unroll
    for (int i = 0; i < 16; ++i) {
        int nl = (i << 2) + w;
        size_t off = (((size_t)(b * NPTS + n0 + nl)) << 6) + lane;
        smx[nl][lane] = tmax[off];
        smn[nl][lane] = tmin[off];
    }
    __syncthreads();
    const float inv_cnt = 1.0f / ((float)BATCH * NPTS * KNN);
    #pragma unroll
    for (int i = 0; i < 16; ++i) {
        int o = (i << 2) + w;
        float s1 = S1[o], s2 = S2[o];
        float mean = s1 * inv_cnt;
        float var = fmaf(-mean, mean, s2 * inv_cnt);
        float rs = rsqrtf(var + BN_EPS);
        float sc = gamma[o] * rs;
        float sh = beta[o] - mean * sc;
        float tv = (sc >= 0.f) ? smx[lane][o] : smn[lane][o];
        float y = fmaf(tv, sc, sh);
        y = (y >= 0.f) ? y : NEG_SLOPE * y;
        out[((size_t)(b * 64 + o)) * NPTS + n0 + lane] = y;
    }
}

// ---------------------------------------------------------------------------
extern "C" void kernel_launch(void* const* d_in, const int* in_sizes, int n_in,
                              void* d_out, int out_size, void* d_ws, size_t ws_size,
                              hipStream_t stream) {
    const float* x     = (const float*)d_in[0];   // [8,64,4096]
    const float* W     = (const float*)d_in[1];   // [64,128]
    const float* gamma = (const float*)d_in[2];   // [64]
    const float* beta  = (const float*)d_in[3];   // [64]
    float* out = (float*)d_out;                   // [8,64,4096]

    float* ws = (float*)d_ws;
    const size_t SECT = (size_t)BATCH * NPTS * 64;      // 2,097,152
    float*  xt    = ws;
    float*  pt    = ws + SECT;
    float*  zt    = ws + 2 * SECT;
    float*  sq    = ws + 3 * SECT;                       // 32768
    float*  S1    = ws + 3 * SECT + 32768;               // 64
    float*  S2    = S1 + 64;
    int*    idx20 = (int*)(ws + 3 * SECT + 32768 + 128); // 655,360 ints
    float*  uA    = ws + 3 * SECT + 32768 + 128 + 655360;
    // union A:
    //   phase 1 (prep..refine): xh (SECT ushorts) | knn32 (B*N*32 ushorts)
    //   phase 2 (gather..final): tmx | tmn
    ushort* xh    = (ushort*)uA;                         // SECT ushorts
    ushort* knn32 = (ushort*)(uA + SECT / 2);            // B*N*32 ushorts
    float*  tmx   = uA;                                  // SECT floats
    float*  tmn   = uA + SECT;                           // SECT floats

    hipMemsetAsync(S1, 0, 2 * 64 * sizeof(float), stream);
    k_prep  <<<dim3((BATCH * NPTS) / 256), dim3(256), 0, stream>>>(x, xt, xh, sq);
    k_pz    <<<dim3(BATCH * (NPTS / 64)), dim3(256), 0, stream>>>(xt, W, pt, zt);
    k_knn   <<<dim3(1024), dim3(512), 0, stream>>>(xh, sq, knn32);
    k_refine<<<dim3((BATCH * NPTS) / 8), dim3(256), 0, stream>>>(xt, sq, knn32, idx20);
    k_gather<<<dim3(BATCH * (NPTS / 64)), dim3(256), 0, stream>>>(pt, zt, idx20, tmx, tmn, S1, S2);
    k_final <<<dim3(BATCH * (NPTS / 64)), dim3(256), 0, stream>>>(tmx, tmn, S1, S2, gamma, beta, out);
}